// Round 1
// baseline (56.438 us; speedup 1.0000x reference)
//
#include <hip/hip_runtime.h>

#define LOG2E 1.4426950408889634f
#define C2    2.8853900817779268f   // 2*log2(e)
#define NEGV  -1000000.0f

// Kernel 1: projection + exp precompute.
// rows 0..4095: Eq[b,q,h] = exp2(clamp(C2 * (queries[row,:] @ Wq[:,h]), +-60))
// rows 4096..8191: same with keys/Wk -> Ek.
__global__ __launch_bounds__(256) void proj_exp_kernel(
    const float* __restrict__ queries,
    const float* __restrict__ keys,
    const float* __restrict__ Wq,
    const float* __restrict__ Wk,
    float* __restrict__ Eq,
    float* __restrict__ Ek)
{
    __shared__ float w_lds[64 * 64];
    __shared__ float in_lds[256];

    const int t   = threadIdx.x;
    const int blk = blockIdx.x;          // 0..2047
    const int r0  = blk * 4;             // virtual row among 8192
    const bool isQ = (r0 < 4096);
    const float* __restrict__ W  = isQ ? Wq : Wk;
    const float* __restrict__ in = isQ ? queries : keys;
    float* __restrict__ Eo       = isQ ? Eq : Ek;
    const int rbase = isQ ? r0 : (r0 - 4096);

#pragma unroll
    for (int i = 0; i < 16; ++i)
        w_lds[t + i * 256] = W[t + i * 256];
    in_lds[t] = in[(size_t)rbase * 64 + t];
    __syncthreads();

    const int h  = t & 63;
    const int rl = t >> 6;               // 0..3 local row
    float acc = 0.f;
#pragma unroll
    for (int i = 0; i < 64; ++i)
        acc = fmaf(in_lds[rl * 64 + i], w_lds[i * 64 + h], acc);

    float x = acc * C2;
    x = fminf(fmaxf(x, -60.f), 60.f);    // e^{2x} per factor bounded: product < 2^120, no overflow
    Eo[(size_t)rbase * 64 + t] = __builtin_amdgcn_exp2f(x);
}

// Kernel 2: fused scores + masked softmax + PV.
// Block: 256 threads = 8 q-rows x 32 k-slots. Grid: 8 b x 64 q-tiles = 512.
// score'[q][k] = -2 * sum_h wv[h] * rcp(1 + Eq[q][h]*Ek[k][h])   (== score - sum(wv), softmax-invariant)
__global__ __launch_bounds__(256) void attn_kernel(
    const float* __restrict__ Eq,
    const float* __restrict__ Ek,
    const float* __restrict__ wv,
    const float* __restrict__ V,
    const int* __restrict__ valid_lens,
    float* __restrict__ out)
{
    __shared__ float ek_lds[128 * 68];   // 128-row Ek tile, row stride 68 floats
    __shared__ float p_lds[8][512];
    __shared__ float l_lds[8];

    const int t   = threadIdx.x;
    const int bid = blockIdx.x;          // 0..511
    const int b   = bid >> 6;
    const int q0  = (bid & 63) << 3;
    const int qi  = t >> 5;              // 0..7
    const int ks  = t & 31;              // 0..31
    const int vl  = valid_lens[b];

    // Eq row for this thread's q -> 64 VGPRs (broadcast across the 32 lanes of the qi-group)
    float eqf[64];
    {
        const float4* eq4 = reinterpret_cast<const float4*>(Eq + (size_t)(b * 512 + q0 + qi) * 64);
#pragma unroll
        for (int i = 0; i < 16; ++i) {
            float4 v = eq4[i];
            eqf[4 * i + 0] = v.x; eqf[4 * i + 1] = v.y;
            eqf[4 * i + 2] = v.z; eqf[4 * i + 3] = v.w;
        }
    }

    const float* __restrict__ ekb = Ek + (size_t)b * 512 * 64;

    float s[16];
    const int lr = t >> 4;               // staging: 16 rows x 16 float4-slots
    const int lc = t & 15;

#pragma unroll
    for (int kt = 0; kt < 4; ++kt) {
        __syncthreads();                 // previous tile fully consumed
#pragma unroll
        for (int rr = 0; rr < 8; ++rr) {
            int row = lr + rr * 16;
            float4 v = *reinterpret_cast<const float4*>(ekb + (size_t)(kt * 128 + row) * 64 + lc * 4);
            *reinterpret_cast<float4*>(&ek_lds[row * 68 + lc * 4]) = v;
        }
        __syncthreads();
#pragma unroll
        for (int j = 0; j < 4; ++j) {
            const float* er = &ek_lds[(ks + 32 * j) * 68];
            float a0 = 0.f, a1 = 0.f;
#pragma unroll
            for (int h = 0; h < 64; h += 8) {
                float4 e0 = *reinterpret_cast<const float4*>(er + h);
                float4 e1 = *reinterpret_cast<const float4*>(er + h + 4);
                a0 = fmaf(wv[h + 0], __builtin_amdgcn_rcpf(fmaf(eqf[h + 0], e0.x, 1.f)), a0);
                a0 = fmaf(wv[h + 1], __builtin_amdgcn_rcpf(fmaf(eqf[h + 1], e0.y, 1.f)), a0);
                a0 = fmaf(wv[h + 2], __builtin_amdgcn_rcpf(fmaf(eqf[h + 2], e0.z, 1.f)), a0);
                a0 = fmaf(wv[h + 3], __builtin_amdgcn_rcpf(fmaf(eqf[h + 3], e0.w, 1.f)), a0);
                a1 = fmaf(wv[h + 4], __builtin_amdgcn_rcpf(fmaf(eqf[h + 4], e1.x, 1.f)), a1);
                a1 = fmaf(wv[h + 5], __builtin_amdgcn_rcpf(fmaf(eqf[h + 5], e1.y, 1.f)), a1);
                a1 = fmaf(wv[h + 6], __builtin_amdgcn_rcpf(fmaf(eqf[h + 6], e1.z, 1.f)), a1);
                a1 = fmaf(wv[h + 7], __builtin_amdgcn_rcpf(fmaf(eqf[h + 7], e1.w, 1.f)), a1);
            }
            s[kt * 4 + j] = -2.f * (a0 + a1);
        }
    }

    // mask: position k valid iff k < vl
#pragma unroll
    for (int i = 0; i < 16; ++i) {
        int k = (i >> 2) * 128 + (i & 3) * 32 + ks;
        if (k >= vl) s[i] = NEGV;
    }

    // row softmax across the 32 lanes of this qi-group (each lane holds 16 of 512 scores)
    float m = s[0];
#pragma unroll
    for (int i = 1; i < 16; ++i) m = fmaxf(m, s[i]);
#pragma unroll
    for (int off = 16; off > 0; off >>= 1) m = fmaxf(m, __shfl_xor(m, off));

    float lsum = 0.f;
#pragma unroll
    for (int i = 0; i < 16; ++i) {
        float p = __builtin_amdgcn_exp2f((s[i] - m) * LOG2E);
        s[i] = p;
        lsum += p;
    }
#pragma unroll
    for (int off = 16; off > 0; off >>= 1) lsum += __shfl_xor(lsum, off);

#pragma unroll
    for (int i = 0; i < 16; ++i)
        p_lds[qi][(i >> 2) * 128 + (i & 3) * 32 + ks] = s[i];
    if (ks == 0) l_lds[qi] = lsum;
    __syncthreads();

    // PV: thread (qi, ks) computes out[q0+qi][2*ks], [2*ks+1]
    const float2* __restrict__ Vb = reinterpret_cast<const float2*>(V + (size_t)b * 512 * 64);
    float ox = 0.f, oy = 0.f;
#pragma unroll 8
    for (int k = 0; k < 512; ++k) {
        float pb = p_lds[qi][k];         // broadcast within qi-group
        float2 v = Vb[k * 32 + ks];      // coalesced 8B/lane
        ox = fmaf(pb, v.x, ox);
        oy = fmaf(pb, v.y, oy);
    }
    float li = __builtin_amdgcn_rcpf(l_lds[qi]);
    float2 o2; o2.x = ox * li; o2.y = oy * li;
    reinterpret_cast<float2*>(out + (size_t)(b * 512 + q0 + qi) * 64)[ks] = o2;
}

extern "C" void kernel_launch(void* const* d_in, const int* in_sizes, int n_in,
                              void* d_out, int out_size, void* d_ws, size_t ws_size,
                              hipStream_t stream) {
    (void)in_sizes; (void)n_in; (void)out_size; (void)ws_size;
    const float* queries = (const float*)d_in[0];
    const float* keys    = (const float*)d_in[1];
    const float* values  = (const float*)d_in[2];
    const int*   vlens   = (const int*)d_in[3];
    const float* Wq      = (const float*)d_in[4];
    const float* Wk      = (const float*)d_in[5];
    const float* wv      = (const float*)d_in[6];
    float* out = (float*)d_out;

    float* Eq = (float*)d_ws;                 // 8*512*64 floats = 1 MB
    float* Ek = Eq + 8 * 512 * 64;            // 1 MB

    proj_exp_kernel<<<2048, 256, 0, stream>>>(queries, keys, Wq, Wk, Eq, Ek);
    attn_kernel<<<512, 256, 0, stream>>>(Eq, Ek, wv, values, vlens, out);
}

// Round 2
// 40.615 us; speedup vs baseline: 1.3896x; 1.3896x over previous
//
#include <hip/hip_runtime.h>

#define LOG2E 1.4426950408889634f
#define C2    2.8853900817779268f   // 2*log2(e)
#define NEGV  -1000000.0f

// Kernel 1: projection + exp precompute.
// rows 0..4095: Eq[b,q,h] = exp2(clamp(C2 * (queries[row,:] @ Wq[:,h]), +-60))
// rows 4096..8191: same with keys/Wk -> Ek.
__global__ __launch_bounds__(256) void proj_exp_kernel(
    const float* __restrict__ queries,
    const float* __restrict__ keys,
    const float* __restrict__ Wq,
    const float* __restrict__ Wk,
    float* __restrict__ Eq,
    float* __restrict__ Ek)
{
    __shared__ float w_lds[64 * 64];
    __shared__ float in_lds[256];

    const int t   = threadIdx.x;
    const int blk = blockIdx.x;          // 0..2047
    const int r0  = blk * 4;             // virtual row among 8192
    const bool isQ = (r0 < 4096);
    const float* __restrict__ W  = isQ ? Wq : Wk;
    const float* __restrict__ in = isQ ? queries : keys;
    float* __restrict__ Eo       = isQ ? Eq : Ek;
    const int rbase = isQ ? r0 : (r0 - 4096);

#pragma unroll
    for (int i = 0; i < 16; ++i)
        w_lds[t + i * 256] = W[t + i * 256];
    in_lds[t] = in[(size_t)rbase * 64 + t];
    __syncthreads();

    const int h  = t & 63;
    const int rl = t >> 6;               // 0..3 local row
    float acc = 0.f;
#pragma unroll
    for (int i = 0; i < 64; ++i)
        acc = fmaf(in_lds[rl * 64 + i], w_lds[i * 64 + h], acc);

    float x = acc * C2;
    x = fminf(fmaxf(x, -60.f), 60.f);    // e^{2x} bounded: products < 2^120, no overflow
    Eo[(size_t)rbase * 64 + t] = __builtin_amdgcn_exp2f(x);
}

// Kernel 2: fused scores + masked softmax + PV.
// Block: 256 threads = 4 waves; wave w owns q-row q0+w for the score/softmax
// phase (64 k-slots per lane), then PV re-maps to 4 k-groups x 64 d-columns.
// score'[q][k] = -2 * sum_h wv[h] * rcp(1 + Eq[q][h]*Ek[k][h])   (softmax-invariant shift)
__global__ __launch_bounds__(256, 4) void attn_kernel(
    const float* __restrict__ Eq,
    const float* __restrict__ Ek,
    const float* __restrict__ wv,
    const float* __restrict__ V,
    const int* __restrict__ valid_lens,
    float* __restrict__ out)
{
    __shared__ float ek_lds[64 * 68];    // 64-row Ek tile, row stride 68 floats (also reused for PV partials)
    __shared__ float p_lds[4][512];
    __shared__ float l_lds[4];

    const int t   = threadIdx.x;
    const int bid = blockIdx.x;          // 0..1023
    const int b   = bid >> 7;
    const int q0  = (bid & 127) << 2;
    const int qi  = t >> 6;              // 0..3  == wave id
    const int ks  = t & 63;              // lane
    const int vl  = valid_lens[b];

    // Eq row for this wave's q -> 64 VGPRs (broadcast across lanes)
    float eqf[64];
    {
        const float4* eq4 = reinterpret_cast<const float4*>(Eq + (size_t)(b * 512 + q0 + qi) * 64);
#pragma unroll
        for (int i = 0; i < 16; ++i) {
            float4 v = eq4[i];
            eqf[4 * i + 0] = v.x; eqf[4 * i + 1] = v.y;
            eqf[4 * i + 2] = v.z; eqf[4 * i + 3] = v.w;
        }
    }

    const float* __restrict__ ekb = Ek + (size_t)b * 512 * 64;

    float s[8];
    const int lr = t >> 4;               // staging: 16 rows x 16 float4-slots per pass
    const int lc = t & 15;

#pragma unroll
    for (int kt = 0; kt < 8; ++kt) {
        __syncthreads();                 // previous tile fully consumed
#pragma unroll
        for (int rr = 0; rr < 4; ++rr) {
            int row = lr + rr * 16;
            float4 v = *reinterpret_cast<const float4*>(ekb + (size_t)(kt * 64 + row) * 64 + lc * 4);
            *reinterpret_cast<float4*>(&ek_lds[row * 68 + lc * 4]) = v;
        }
        __syncthreads();

        const float* er = &ek_lds[ks * 68];
        float a0 = 0.f, a1 = 0.f;
#pragma unroll
        for (int h = 0; h < 64; h += 8) {
            float4 e0 = *reinterpret_cast<const float4*>(er + h);
            float4 e1 = *reinterpret_cast<const float4*>(er + h + 4);
            a0 = fmaf(wv[h + 0], __builtin_amdgcn_rcpf(fmaf(eqf[h + 0], e0.x, 1.f)), a0);
            a0 = fmaf(wv[h + 1], __builtin_amdgcn_rcpf(fmaf(eqf[h + 1], e0.y, 1.f)), a0);
            a0 = fmaf(wv[h + 2], __builtin_amdgcn_rcpf(fmaf(eqf[h + 2], e0.z, 1.f)), a0);
            a0 = fmaf(wv[h + 3], __builtin_amdgcn_rcpf(fmaf(eqf[h + 3], e0.w, 1.f)), a0);
            a1 = fmaf(wv[h + 4], __builtin_amdgcn_rcpf(fmaf(eqf[h + 4], e1.x, 1.f)), a1);
            a1 = fmaf(wv[h + 5], __builtin_amdgcn_rcpf(fmaf(eqf[h + 5], e1.y, 1.f)), a1);
            a1 = fmaf(wv[h + 6], __builtin_amdgcn_rcpf(fmaf(eqf[h + 6], e1.z, 1.f)), a1);
            a1 = fmaf(wv[h + 7], __builtin_amdgcn_rcpf(fmaf(eqf[h + 7], e1.w, 1.f)), a1);
        }
        s[kt] = -2.f * (a0 + a1);
    }

    // mask: position k valid iff k < vl
#pragma unroll
    for (int i = 0; i < 8; ++i) {
        int k = i * 64 + ks;
        if (k >= vl) s[i] = NEGV;
    }

    // row softmax across the full 64-lane wave (each lane holds 8 of 512 scores)
    float m = s[0];
#pragma unroll
    for (int i = 1; i < 8; ++i) m = fmaxf(m, s[i]);
#pragma unroll
    for (int off = 32; off > 0; off >>= 1) m = fmaxf(m, __shfl_xor(m, off));

    float lsum = 0.f;
#pragma unroll
    for (int i = 0; i < 8; ++i) {
        float p = __builtin_amdgcn_exp2f((s[i] - m) * LOG2E);
        s[i] = p;
        lsum += p;
    }
#pragma unroll
    for (int off = 32; off > 0; off >>= 1) lsum += __shfl_xor(lsum, off);

#pragma unroll
    for (int i = 0; i < 8; ++i)
        p_lds[qi][i * 64 + ks] = s[i];
    if (ks == 0) l_lds[qi] = lsum;
    __syncthreads();

    // PV: thread = (kg = t>>6, d = t&63). Each V row loaded exactly once per block.
    const int kg = qi;                   // k-group 0..3 (k range [kg*128, kg*128+128))
    const int d  = ks;
    const float* __restrict__ Vb = V + (size_t)b * 512 * 64;
    float acc0 = 0.f, acc1 = 0.f, acc2 = 0.f, acc3 = 0.f;
    const int kbeg = kg * 128;
#pragma unroll 4
    for (int k0 = kbeg; k0 < kbeg + 128; k0 += 4) {
        float4 p0 = *reinterpret_cast<const float4*>(&p_lds[0][k0]);   // broadcast b128
        float4 p1 = *reinterpret_cast<const float4*>(&p_lds[1][k0]);
        float4 p2 = *reinterpret_cast<const float4*>(&p_lds[2][k0]);
        float4 p3 = *reinterpret_cast<const float4*>(&p_lds[3][k0]);
        float v0 = Vb[(size_t)(k0 + 0) * 64 + d];
        float v1 = Vb[(size_t)(k0 + 1) * 64 + d];
        float v2 = Vb[(size_t)(k0 + 2) * 64 + d];
        float v3 = Vb[(size_t)(k0 + 3) * 64 + d];
        acc0 = fmaf(p0.x, v0, acc0); acc0 = fmaf(p0.y, v1, acc0);
        acc0 = fmaf(p0.z, v2, acc0); acc0 = fmaf(p0.w, v3, acc0);
        acc1 = fmaf(p1.x, v0, acc1); acc1 = fmaf(p1.y, v1, acc1);
        acc1 = fmaf(p1.z, v2, acc1); acc1 = fmaf(p1.w, v3, acc1);
        acc2 = fmaf(p2.x, v0, acc2); acc2 = fmaf(p2.y, v1, acc2);
        acc2 = fmaf(p2.z, v2, acc2); acc2 = fmaf(p2.w, v3, acc2);
        acc3 = fmaf(p3.x, v0, acc3); acc3 = fmaf(p3.y, v1, acc3);
        acc3 = fmaf(p3.z, v2, acc3); acc3 = fmaf(p3.w, v3, acc3);
    }
    // partials: part[kg][q][d] in the (now free) ek_lds buffer
    ek_lds[(kg * 4 + 0) * 64 + d] = acc0;
    ek_lds[(kg * 4 + 1) * 64 + d] = acc1;
    ek_lds[(kg * 4 + 2) * 64 + d] = acc2;
    ek_lds[(kg * 4 + 3) * 64 + d] = acc3;
    __syncthreads();

    // combine: thread (q = t>>6, d = t&63)
    const int q = qi;
    float li = __builtin_amdgcn_rcpf(l_lds[q]);
    float o = ek_lds[(0 * 4 + q) * 64 + d] + ek_lds[(1 * 4 + q) * 64 + d]
            + ek_lds[(2 * 4 + q) * 64 + d] + ek_lds[(3 * 4 + q) * 64 + d];
    out[(size_t)(b * 512 + q0 + q) * 64 + d] = o * li;
}

extern "C" void kernel_launch(void* const* d_in, const int* in_sizes, int n_in,
                              void* d_out, int out_size, void* d_ws, size_t ws_size,
                              hipStream_t stream) {
    (void)in_sizes; (void)n_in; (void)out_size; (void)ws_size;
    const float* queries = (const float*)d_in[0];
    const float* keys    = (const float*)d_in[1];
    const float* values  = (const float*)d_in[2];
    const int*   vlens   = (const int*)d_in[3];
    const float* Wq      = (const float*)d_in[4];
    const float* Wk      = (const float*)d_in[5];
    const float* wv      = (const float*)d_in[6];
    float* out = (float*)d_out;

    float* Eq = (float*)d_ws;                 // 8*512*64 floats = 1 MB
    float* Ek = Eq + 8 * 512 * 64;            // 1 MB

    proj_exp_kernel<<<2048, 256, 0, stream>>>(queries, keys, Wq, Wk, Eq, Ek);
    attn_kernel<<<1024, 256, 0, stream>>>(Eq, Ek, wv, values, vlens, out);
}